// Round 4
// baseline (323.067 us; speedup 1.0000x reference)
//
#include <hip/hip_runtime.h>

#define B_ 64
#define D_ 256
#define T_ 1024
#define NC_ 1024
#define DT_ (D_ * T_)              // 262144
#define NPTS_ (B_ * T_)            // 65536

#define QSZ_   16777216            // B*D*T
#define LOSS_OFF 16777216
#define CMT_OFF  16777217
#define IDX_OFF  16777218
#define PERP_OFF 16842754

typedef _Float16 half8 __attribute__((ext_vector_type(8)));
typedef float f32x4 __attribute__((ext_vector_type(4)));

// LDS row stride for x tiles: 256 k + 8 pad halves = 264 (528B, 16B-aligned
// rows; A-frag reads land 2-way on banks = free)
#define XROW_ 264
#define XLO_OFF_ (64 * XROW_)      // xs_lo starts here (halfs)

// ---------------- Kernel P: split embed into frag-order hi/lo + f32 norms ---
// ehi/elo layout: frag-major. For code-group g (16 codes), k-chunk kc (32 k),
// lane l: element j holds e[g*16 + (l&15)][kc*32 + (l>>4)*8 + j].
// Stored at half-offset ((g*8 + kc)*64 + l)*8 + j -> wave loads 1KB contiguous.
__global__ void prep_embed(const float* __restrict__ embed,
                           _Float16* __restrict__ ehi,
                           _Float16* __restrict__ elo,
                           float* __restrict__ normf) {
  int g = blockIdx.x;              // 64 blocks
  int tid = threadIdx.x;           // 256
  int w = tid >> 6, l = tid & 63;

#pragma unroll
  for (int ii = 0; ii < 2; ++ii) {
    int kc = w * 2 + ii;
    int code = g * 16 + (l & 15);
    int k0 = kc * 32 + (l >> 4) * 8;
    const float* src = embed + (size_t)code * D_ + k0;
    half8 hh, ll;
#pragma unroll
    for (int j = 0; j < 8; ++j) {
      float v = src[j];
      _Float16 h = (_Float16)v;
      _Float16 lo = (_Float16)(v - (float)h);
      hh[j] = h;
      ll[j] = lo;
    }
    size_t off = ((size_t)(g * 8 + kc) * 64 + l) * 8;
    *(half8*)(ehi + off) = hh;
    *(half8*)(elo + off) = ll;
  }

  // f64-accumulated norms (stored f32): code = g*16 + tid>>4, seg (tid&15)*16
  int code = g * 16 + (tid >> 4);
  int ks = (tid & 15) * 16;
  const float* src = embed + (size_t)code * D_ + ks;
  double s = 0.0;
#pragma unroll
  for (int j = 0; j < 16; ++j) {
    double v = src[j];
    s += v * v;
  }
#pragma unroll
  for (int m = 1; m < 16; m <<= 1) s += __shfl_xor(s, m, 64);
  if ((tid & 15) == 0) normf[code] = (float)s;
}

// ---------------- argmin kernel helpers -------------------------------------
__device__ __forceinline__ void loadB(half8 (&BH)[4], half8 (&BL)[4],
                                      const _Float16* __restrict__ ehi,
                                      const _Float16* __restrict__ elo,
                                      int w, int l, int ng, int kc) {
#pragma unroll
  for (int n = 0; n < 4; ++n) {
    int g = ng * 16 + w * 4 + n;
    size_t off = ((size_t)(g * 8 + kc) * 64 + l) * 8;
    BH[n] = *(const half8*)(ehi + off);
    BL[n] = *(const half8*)(elo + off);
  }
}

__device__ __forceinline__ void loadA(half8 (&AH)[4], half8 (&AL)[4],
                                      const _Float16* xs, int lrow, int lk,
                                      int kc) {
#pragma unroll
  for (int m = 0; m < 4; ++m) {
    const _Float16* p = &xs[(m * 16 + lrow) * XROW_ + kc * 32 + lk];
    AH[m] = *(const half8*)p;
    AL[m] = *(const half8*)(p + XLO_OFF_);
  }
}

__device__ __forceinline__ void mfma48(f32x4 (&acc)[4][4], half8 (&AH)[4],
                                       half8 (&AL)[4], half8 (&BH)[4],
                                       half8 (&BL)[4]) {
#pragma unroll
  for (int m = 0; m < 4; ++m)
#pragma unroll
    for (int n = 0; n < 4; ++n) {
      acc[m][n] =
          __builtin_amdgcn_mfma_f32_16x16x32_f16(AH[m], BH[n], acc[m][n], 0, 0, 0);
      acc[m][n] =
          __builtin_amdgcn_mfma_f32_16x16x32_f16(AL[m], BH[n], acc[m][n], 0, 0, 0);
      acc[m][n] =
          __builtin_amdgcn_mfma_f32_16x16x32_f16(AH[m], BL[n], acc[m][n], 0, 0, 0);
    }
}

// ---------------- Kernel B: MFMA distance GEMM + argmin ---------------------
// 1024 blocks x 256 threads (4 waves). Block owns 64 points (one b, 64 t).
// x tile staged once in LDS as f16 hi/lo. Wave covers 64 codes per ng (4
// N-frags), 4 ngs -> 256 codes/wave. A and B operand streams both double-
// buffered one step ahead; the f32 fold (key = nrm - 2*dot, xn2-free) runs
// while the next ng's first B-set is in flight.
__global__ __launch_bounds__(256, 2) void argmin_kernel(
    const float* __restrict__ inputs, const _Float16* __restrict__ ehi,
    const _Float16* __restrict__ elo, const float* __restrict__ normf,
    float* __restrict__ idx_out, int* __restrict__ counts,
    double* __restrict__ mse_acc) {
  __shared__ _Float16 xs[2 * 64 * XROW_];  // hi then lo, 67584 B
  __shared__ float normf_lds[1024];        // 4096 B
  __shared__ double part[256];             // 2048 B (aliased by cand at tail)
  __shared__ double xn2s[64];              // 512 B

  float* candv = (float*)part;             // [4][64] floats, tail only
  int* candi = (int*)&part[128];           // [4][64] ints, tail only

  int tid = threadIdx.x;
  int blk = blockIdx.x;            // point block: 64 points
  int b = blk >> 4, t0 = (blk & 15) * 64;
  size_t base = (size_t)b * DT_ + t0;

  int w = tid >> 6, l = tid & 63;
  int lrow = l & 15;
  int lk = (l >> 4) * 8;

  // issue the first B set immediately: flies during the whole staging phase
  half8 bh0[4], bl0[4], bh1[4], bl1[4];
  loadB(bh0, bl0, ehi, elo, w, l, 0, 0);

  // ---- stage x tile: f32 -> (hi,lo) f16, transpose [d][t] -> [t][k=d] ----
  {
    int t = tid & 63, dgrp = tid >> 6;
    const float* src = inputs + base + t;
    double s = 0.0;
#pragma unroll 4
    for (int i = 0; i < 32; ++i) {
      int d = dgrp * 64 + i * 2;
      float v0 = src[(size_t)d * T_];
      float v1 = src[(size_t)(d + 1) * T_];
      s += (double)v0 * v0 + (double)v1 * v1;
      _Float16 h0 = (_Float16)v0, h1 = (_Float16)v1;
      _Float16 e0 = (_Float16)(v0 - (float)h0);
      _Float16 e1 = (_Float16)(v1 - (float)h1);
      union {
        _Float16 h[2];
        unsigned u;
      } ph, pl;
      ph.h[0] = h0; ph.h[1] = h1;
      pl.h[0] = e0; pl.h[1] = e1;
      *(unsigned*)&xs[t * XROW_ + d] = ph.u;
      *(unsigned*)&xs[XLO_OFF_ + t * XROW_ + d] = pl.u;
    }
    part[tid] = s;
    // stage f32 norms table (4 KB)
    ((float4*)normf_lds)[tid] = ((const float4*)normf)[tid];
  }
  __syncthreads();
  if (tid < 64)
    xn2s[tid] = part[tid] + part[64 + tid] + part[128 + tid] + part[192 + tid];
  __syncthreads();

  float bestv[4][4];
  int besti[4][4];
#pragma unroll
  for (int m = 0; m < 4; ++m)
#pragma unroll
    for (int r = 0; r < 4; ++r) {
      bestv[m][r] = 1e30f;
      besti[m][r] = 0;
    }

  half8 ah0[4], al0[4], ah1[4], al1[4];
  loadA(ah0, al0, xs, lrow, lk, 0);

#pragma unroll 1
  for (int ng = 0; ng < 4; ++ng) {
    f32x4 acc[4][4];
#pragma unroll
    for (int m = 0; m < 4; ++m)
#pragma unroll
      for (int n = 0; n < 4; ++n) acc[m][n] = (f32x4){0.f, 0.f, 0.f, 0.f};

    int ngn = (ng + 1) & 3;
    // kc steps, A and B双-buffered one step ahead
    loadB(bh1, bl1, ehi, elo, w, l, ng, 1);
    loadA(ah1, al1, xs, lrow, lk, 1);
    mfma48(acc, ah0, al0, bh0, bl0);

    loadB(bh0, bl0, ehi, elo, w, l, ng, 2);
    loadA(ah0, al0, xs, lrow, lk, 2);
    mfma48(acc, ah1, al1, bh1, bl1);

    loadB(bh1, bl1, ehi, elo, w, l, ng, 3);
    loadA(ah1, al1, xs, lrow, lk, 3);
    mfma48(acc, ah0, al0, bh0, bl0);

    loadB(bh0, bl0, ehi, elo, w, l, ng, 4);
    loadA(ah0, al0, xs, lrow, lk, 4);
    mfma48(acc, ah1, al1, bh1, bl1);

    loadB(bh1, bl1, ehi, elo, w, l, ng, 5);
    loadA(ah1, al1, xs, lrow, lk, 5);
    mfma48(acc, ah0, al0, bh0, bl0);

    loadB(bh0, bl0, ehi, elo, w, l, ng, 6);
    loadA(ah0, al0, xs, lrow, lk, 6);
    mfma48(acc, ah1, al1, bh1, bl1);

    loadB(bh1, bl1, ehi, elo, w, l, ng, 7);
    loadA(ah1, al1, xs, lrow, lk, 7);
    mfma48(acc, ah0, al0, bh0, bl0);

    loadB(bh0, bl0, ehi, elo, w, l, ngn, 0);   // next ng's first set
    loadA(ah0, al0, xs, lrow, lk, 0);
    mfma48(acc, ah1, al1, bh1, bl1);

    // ---- f32 fold: key = nrm - 2*dot (xn2-free; order-equivalent) ----
#pragma unroll
    for (int n = 0; n < 4; ++n) {
      int c = (ng * 16 + w * 4 + n) * 16 + lrow;
      float nf = normf_lds[c];
#pragma unroll
      for (int m = 0; m < 4; ++m)
#pragma unroll
        for (int r = 0; r < 4; ++r) {
          float df = fmaf(-2.0f, acc[m][n][r], nf);
          if (df < bestv[m][r]) {
            bestv[m][r] = df;
            besti[m][r] = c;
          }
        }
    }
  }

  // reduce across the 16 code-lanes of each quarter
#pragma unroll
  for (int msk = 1; msk < 16; msk <<= 1) {
#pragma unroll
    for (int m = 0; m < 4; ++m)
#pragma unroll
      for (int r = 0; r < 4; ++r) {
        float ov = __shfl_xor(bestv[m][r], msk, 64);
        int oi = __shfl_xor(besti[m][r], msk, 64);
        if (ov < bestv[m][r] || (ov == bestv[m][r] && oi < besti[m][r])) {
          bestv[m][r] = ov;
          besti[m][r] = oi;
        }
      }
  }
  if (lrow == 0) {
    int q = l >> 4;
#pragma unroll
    for (int m = 0; m < 4; ++m)
#pragma unroll
      for (int r = 0; r < 4; ++r) {
        candv[w * 64 + m * 16 + q * 4 + r] = bestv[m][r];
        candi[w * 64 + m * 16 + q * 4 + r] = besti[m][r];
      }
  }
  __syncthreads();

  if (tid < 64) {
    float bv = candv[tid];
    int bi = candi[tid];
#pragma unroll
    for (int w2 = 1; w2 < 4; ++w2) {
      float ov = candv[w2 * 64 + tid];
      int oi = candi[w2 * 64 + tid];
      if (ov < bv || (ov == bv && oi < bi)) {
        bv = ov;
        bi = oi;
      }
    }
    int p = blk * 64 + tid;
    idx_out[p] = (float)bi;
    atomicAdd(&counts[bi], 1);
    // MSE: dist = ||x||^2 + (nrm - 2*dot) = xn2 + key
    double s = xn2s[tid] + (double)bv;
    for (int msk = 32; msk; msk >>= 1) s += __shfl_down(s, msk, 64);
    if (tid == 0) atomicAdd(mse_acc, s);
  }
}

// ---------------- Kernel C: gather quantized rows, coalesced write ----------
__global__ __launch_bounds__(256) void quantize_kernel(
    const float* __restrict__ embed, const float* __restrict__ idx_f,
    float* __restrict__ qout) {
  __shared__ float qs[64 * 257];
  __shared__ int lidx[64];

  int tid = threadIdx.x;
  int bx = blockIdx.x;
  int b = bx >> 4;
  int t0 = (bx & 15) * 64;

  if (tid < 64) lidx[tid] = (int)idx_f[b * T_ + t0 + tid];
  __syncthreads();

#pragma unroll 4
  for (int p = 0; p < 64; ++p) {
    qs[p * 257 + tid] = embed[(size_t)lidx[p] * D_ + tid];
  }
  __syncthreads();

  size_t base = (size_t)b * DT_ + t0;
#pragma unroll 4
  for (int i = 0; i < 64; ++i) {
    int d = i * 4 + (tid >> 6);
    int p = tid & 63;
    qout[base + (size_t)d * T_ + p] = qs[p * 257 + d];
  }
}

// ---------------- Kernel D: finalize scalars --------------------------------
__global__ void finalize_kernel(const int* __restrict__ counts,
                                const double* __restrict__ mse_acc,
                                float* __restrict__ out) {
  int tid = threadIdx.x;  // 1024
  double p = (double)counts[tid] / (double)NPTS_;
  double s = p * log(p + 1e-10);
  for (int m = 32; m; m >>= 1) s += __shfl_down(s, m, 64);
  __shared__ double red[16];
  if ((tid & 63) == 0) red[tid >> 6] = s;
  __syncthreads();
  if (tid == 0) {
    double tot = 0.0;
    for (int i = 0; i < 16; ++i) tot += red[i];
    double mse = *mse_acc / (double)QSZ_;
    out[LOSS_OFF] = (float)(mse * 1.2);
    out[CMT_OFF] = (float)mse;
    out[PERP_OFF] = (float)exp(-tot);
  }
}

// ---------------- launch ----------------------------------------------------
extern "C" void kernel_launch(void* const* d_in, const int* in_sizes, int n_in,
                              void* d_out, int out_size, void* d_ws,
                              size_t ws_size, hipStream_t stream) {
  const float* inputs = (const float*)d_in[0];
  const float* embed = (const float*)d_in[1];
  float* out = (float*)d_out;

  char* ws = (char*)d_ws;
  _Float16* ehi = (_Float16*)ws;                         // 512 KB
  _Float16* elo = (_Float16*)(ws + 524288);              // 512 KB
  float* normf = (float*)(ws + 1048576);                 // 4 KB
  int* counts = (int*)(ws + 1048576 + 4096);             // 4 KB
  double* mse = (double*)(ws + 1048576 + 8192);          // 8 B

  hipMemsetAsync(ws + 1048576 + 4096, 0, 4096 + 8, stream);

  prep_embed<<<64, 256, 0, stream>>>(embed, ehi, elo, normf);
  argmin_kernel<<<1024, 256, 0, stream>>>(inputs, ehi, elo, normf,
                                          out + IDX_OFF, counts, mse);
  quantize_kernel<<<1024, 256, 0, stream>>>(embed, out + IDX_OFF, out);
  finalize_kernel<<<1, 1024, 0, stream>>>(counts, mse, out);
}

// Round 5
// 151.184 us; speedup vs baseline: 2.1369x; 2.1369x over previous
//
#include <hip/hip_runtime.h>

#define B_ 64
#define D_ 256
#define T_ 1024
#define NC_ 1024
#define DT_ (D_ * T_)              // 262144
#define NPTS_ (B_ * T_)            // 65536

#define QSZ_   16777216            // B*D*T
#define LOSS_OFF 16777216
#define CMT_OFF  16777217
#define IDX_OFF  16777218
#define PERP_OFF 16842754

typedef _Float16 half8 __attribute__((ext_vector_type(8)));
typedef float f32x4 __attribute__((ext_vector_type(4)));

// LDS row stride for x tiles: 256 k + 8 pad halves = 264 (528B, 16B-aligned
// rows; A-frag reads land 2-way on banks = free)
#define XROW_ 264
#define XLO_OFF_ (64 * XROW_)      // xs_lo starts here (halfs)

// ---------------- Kernel P: split embed into frag-order hi/lo + f32 norms ---
// ehi/elo layout: frag-major. For code-group g (16 codes), k-chunk kc (32 k),
// lane l: element j holds e[g*16 + (l&15)][kc*32 + (l>>4)*8 + j].
// Stored at half-offset ((g*8 + kc)*64 + l)*8 + j -> wave loads 1KB contiguous.
__global__ void prep_embed(const float* __restrict__ embed,
                           _Float16* __restrict__ ehi,
                           _Float16* __restrict__ elo,
                           float* __restrict__ normf) {
  int g = blockIdx.x;              // 64 blocks
  int tid = threadIdx.x;           // 256
  int w = tid >> 6, l = tid & 63;

#pragma unroll
  for (int ii = 0; ii < 2; ++ii) {
    int kc = w * 2 + ii;
    int code = g * 16 + (l & 15);
    int k0 = kc * 32 + (l >> 4) * 8;
    const float* src = embed + (size_t)code * D_ + k0;
    half8 hh, ll;
#pragma unroll
    for (int j = 0; j < 8; ++j) {
      float v = src[j];
      _Float16 h = (_Float16)v;
      _Float16 lo = (_Float16)(v - (float)h);
      hh[j] = h;
      ll[j] = lo;
    }
    size_t off = ((size_t)(g * 8 + kc) * 64 + l) * 8;
    *(half8*)(ehi + off) = hh;
    *(half8*)(elo + off) = ll;
  }

  // f64-accumulated norms (stored f32): code = g*16 + tid>>4, seg (tid&15)*16
  int code = g * 16 + (tid >> 4);
  int ks = (tid & 15) * 16;
  const float* src = embed + (size_t)code * D_ + ks;
  double s = 0.0;
#pragma unroll
  for (int j = 0; j < 16; ++j) {
    double v = src[j];
    s += v * v;
  }
#pragma unroll
  for (int m = 1; m < 16; m <<= 1) s += __shfl_xor(s, m, 64);
  if ((tid & 15) == 0) normf[code] = (float)s;
}

// ---------------- Kernel B: MFMA distance GEMM + argmin ---------------------
// 1024 blocks x 256 threads (4 waves). Block owns 64 points (one b, 64 t).
// x tile staged once in LDS as f16 hi/lo. Wave covers 64 codes per ng (4
// N-frags), 4 ngs -> 256 codes/wave. Loads single-buffered per kc step,
// unroll-2 window — compiler schedules (R2-proven, no spills). Fold is pure
// f32, xn2-free: key = nrm - 2*dot (argmin-equivalent per point).
__global__ __launch_bounds__(256, 2) void argmin_kernel(
    const float* __restrict__ inputs, const _Float16* __restrict__ ehi,
    const _Float16* __restrict__ elo, const float* __restrict__ normf,
    float* __restrict__ idx_out, int* __restrict__ counts,
    double* __restrict__ mse_acc) {
  __shared__ _Float16 xs[2 * 64 * XROW_];  // hi then lo, 67584 B
  __shared__ float normf_lds[1024];        // 4096 B
  __shared__ double part[256];             // 2048 B (aliased by cand at tail)
  __shared__ double xn2s[64];              // 512 B

  float* candv = (float*)part;             // [4][64] floats, tail only
  int* candi = (int*)&part[128];           // [4][64] ints, tail only

  int tid = threadIdx.x;
  int blk = blockIdx.x;            // point block: 64 points
  int b = blk >> 4, t0 = (blk & 15) * 64;
  size_t base = (size_t)b * DT_ + t0;

  // ---- stage x tile: f32 -> (hi,lo) f16, transpose [d][t] -> [t][k=d] ----
  {
    int t = tid & 63, dgrp = tid >> 6;
    const float* src = inputs + base + t;
    double s = 0.0;
#pragma unroll 4
    for (int i = 0; i < 32; ++i) {
      int d = dgrp * 64 + i * 2;
      float v0 = src[(size_t)d * T_];
      float v1 = src[(size_t)(d + 1) * T_];
      s += (double)v0 * v0 + (double)v1 * v1;
      _Float16 h0 = (_Float16)v0, h1 = (_Float16)v1;
      _Float16 e0 = (_Float16)(v0 - (float)h0);
      _Float16 e1 = (_Float16)(v1 - (float)h1);
      union {
        _Float16 h[2];
        unsigned u;
      } ph, pl;
      ph.h[0] = h0; ph.h[1] = h1;
      pl.h[0] = e0; pl.h[1] = e1;
      *(unsigned*)&xs[t * XROW_ + d] = ph.u;
      *(unsigned*)&xs[XLO_OFF_ + t * XROW_ + d] = pl.u;
    }
    part[tid] = s;
    // stage f32 norms table (4 KB)
    ((float4*)normf_lds)[tid] = ((const float4*)normf)[tid];
  }
  __syncthreads();
  if (tid < 64)
    xn2s[tid] = part[tid] + part[64 + tid] + part[128 + tid] + part[192 + tid];
  __syncthreads();

  int w = tid >> 6, l = tid & 63;
  int lrow = l & 15;
  int lk = (l >> 4) * 8;

  // per-lane point slots: p_local = m*16 + (l>>4)*4 + r
  float bestv[4][4];
  int besti[4][4];
#pragma unroll
  for (int m = 0; m < 4; ++m)
#pragma unroll
    for (int r = 0; r < 4; ++r) {
      bestv[m][r] = 1e30f;
      besti[m][r] = 0;
    }

#pragma unroll 1
  for (int ng = 0; ng < 4; ++ng) {
    f32x4 acc[4][4];
#pragma unroll
    for (int m = 0; m < 4; ++m)
#pragma unroll
      for (int n = 0; n < 4; ++n) acc[m][n] = (f32x4){0.f, 0.f, 0.f, 0.f};

#pragma unroll 2
    for (int kc = 0; kc < 8; ++kc) {
      // global B loads first (longest latency)
      half8 bh[4], bl[4];
#pragma unroll
      for (int n = 0; n < 4; ++n) {
        int g = ng * 16 + w * 4 + n;
        size_t off = ((size_t)(g * 8 + kc) * 64 + l) * 8;
        bh[n] = *(const half8*)(ehi + off);
        bl[n] = *(const half8*)(elo + off);
      }
      half8 ah[4], al[4];
#pragma unroll
      for (int m = 0; m < 4; ++m) {
        const _Float16* p = &xs[(m * 16 + lrow) * XROW_ + kc * 32 + lk];
        ah[m] = *(const half8*)p;
        al[m] = *(const half8*)(p + XLO_OFF_);
      }
#pragma unroll
      for (int m = 0; m < 4; ++m)
#pragma unroll
        for (int n = 0; n < 4; ++n) {
          acc[m][n] =
              __builtin_amdgcn_mfma_f32_16x16x32_f16(ah[m], bh[n], acc[m][n], 0, 0, 0);
          acc[m][n] =
              __builtin_amdgcn_mfma_f32_16x16x32_f16(al[m], bh[n], acc[m][n], 0, 0, 0);
          acc[m][n] =
              __builtin_amdgcn_mfma_f32_16x16x32_f16(ah[m], bl[n], acc[m][n], 0, 0, 0);
        }
    }

    // ---- f32 fold: key = nrm - 2*dot (xn2-free; strict < keeps low-index
    // ties because c is strictly increasing per thread) ----
#pragma unroll
    for (int n = 0; n < 4; ++n) {
      int c = ng * 256 + w * 64 + n * 16 + lrow;
      float nf = normf_lds[c];
#pragma unroll
      for (int m = 0; m < 4; ++m)
#pragma unroll
        for (int r = 0; r < 4; ++r) {
          float df = fmaf(-2.0f, acc[m][n][r], nf);
          if (df < bestv[m][r]) {
            bestv[m][r] = df;
            besti[m][r] = c;
          }
        }
    }
  }

  // reduce across the 16 code-lanes of each quarter
#pragma unroll
  for (int msk = 1; msk < 16; msk <<= 1) {
#pragma unroll
    for (int m = 0; m < 4; ++m)
#pragma unroll
      for (int r = 0; r < 4; ++r) {
        float ov = __shfl_xor(bestv[m][r], msk, 64);
        int oi = __shfl_xor(besti[m][r], msk, 64);
        if (ov < bestv[m][r] || (ov == bestv[m][r] && oi < besti[m][r])) {
          bestv[m][r] = ov;
          besti[m][r] = oi;
        }
      }
  }
  if (lrow == 0) {
    int q = l >> 4;
#pragma unroll
    for (int m = 0; m < 4; ++m)
#pragma unroll
      for (int r = 0; r < 4; ++r) {
        candv[w * 64 + m * 16 + q * 4 + r] = bestv[m][r];
        candi[w * 64 + m * 16 + q * 4 + r] = besti[m][r];
      }
  }
  __syncthreads();

  if (tid < 64) {
    float bv = candv[tid];
    int bi = candi[tid];
#pragma unroll
    for (int w2 = 1; w2 < 4; ++w2) {
      float ov = candv[w2 * 64 + tid];
      int oi = candi[w2 * 64 + tid];
      if (ov < bv || (ov == bv && oi < bi)) {
        bv = ov;
        bi = oi;
      }
    }
    int p = blk * 64 + tid;
    idx_out[p] = (float)bi;
    atomicAdd(&counts[bi], 1);
    // MSE: dist = ||x||^2 + (nrm - 2*dot) = xn2 + key
    double s = xn2s[tid] + (double)bv;
    for (int msk = 32; msk; msk >>= 1) s += __shfl_down(s, msk, 64);
    if (tid == 0) atomicAdd(mse_acc, s);
  }
}

// ---------------- Kernel C: gather quantized rows, coalesced write ----------
__global__ __launch_bounds__(256) void quantize_kernel(
    const float* __restrict__ embed, const float* __restrict__ idx_f,
    float* __restrict__ qout) {
  __shared__ float qs[64 * 257];
  __shared__ int lidx[64];

  int tid = threadIdx.x;
  int bx = blockIdx.x;
  int b = bx >> 4;
  int t0 = (bx & 15) * 64;

  if (tid < 64) lidx[tid] = (int)idx_f[b * T_ + t0 + tid];
  __syncthreads();

#pragma unroll 4
  for (int p = 0; p < 64; ++p) {
    qs[p * 257 + tid] = embed[(size_t)lidx[p] * D_ + tid];
  }
  __syncthreads();

  size_t base = (size_t)b * DT_ + t0;
#pragma unroll 4
  for (int i = 0; i < 64; ++i) {
    int d = i * 4 + (tid >> 6);
    int p = tid & 63;
    qout[base + (size_t)d * T_ + p] = qs[p * 257 + d];
  }
}

// ---------------- Kernel D: finalize scalars --------------------------------
__global__ void finalize_kernel(const int* __restrict__ counts,
                                const double* __restrict__ mse_acc,
                                float* __restrict__ out) {
  int tid = threadIdx.x;  // 1024
  double p = (double)counts[tid] / (double)NPTS_;
  double s = p * log(p + 1e-10);
  for (int m = 32; m; m >>= 1) s += __shfl_down(s, m, 64);
  __shared__ double red[16];
  if ((tid & 63) == 0) red[tid >> 6] = s;
  __syncthreads();
  if (tid == 0) {
    double tot = 0.0;
    for (int i = 0; i < 16; ++i) tot += red[i];
    double mse = *mse_acc / (double)QSZ_;
    out[LOSS_OFF] = (float)(mse * 1.2);
    out[CMT_OFF] = (float)mse;
    out[PERP_OFF] = (float)exp(-tot);
  }
}

// ---------------- launch ----------------------------------------------------
extern "C" void kernel_launch(void* const* d_in, const int* in_sizes, int n_in,
                              void* d_out, int out_size, void* d_ws,
                              size_t ws_size, hipStream_t stream) {
  const float* inputs = (const float*)d_in[0];
  const float* embed = (const float*)d_in[1];
  float* out = (float*)d_out;

  char* ws = (char*)d_ws;
  _Float16* ehi = (_Float16*)ws;                         // 512 KB
  _Float16* elo = (_Float16*)(ws + 524288);              // 512 KB
  float* normf = (float*)(ws + 1048576);                 // 4 KB
  int* counts = (int*)(ws + 1048576 + 4096);             // 4 KB
  double* mse = (double*)(ws + 1048576 + 8192);          // 8 B

  hipMemsetAsync(ws + 1048576 + 4096, 0, 4096 + 8, stream);

  prep_embed<<<64, 256, 0, stream>>>(embed, ehi, elo, normf);
  argmin_kernel<<<1024, 256, 0, stream>>>(inputs, ehi, elo, normf,
                                          out + IDX_OFF, counts, mse);
  quantize_kernel<<<1024, 256, 0, stream>>>(embed, out + IDX_OFF, out);
  finalize_kernel<<<1, 1024, 0, stream>>>(counts, mse, out);
}